// Round 14
// baseline (340.739 us; speedup 1.0000x reference)
//
#include <hip/hip_runtime.h>

typedef __attribute__((ext_vector_type(8))) short bf16x8;
typedef __attribute__((ext_vector_type(4))) float f32x4;
typedef __attribute__((ext_vector_type(2))) float f32x2;

#define KNBR 32
#define WAVES 8         // waves per block
#define GQ   2          // queries per wave, software-pipelined

union Frag { int4 i; bf16x8 b; };

__device__ __forceinline__ unsigned short f2bf(float f) {
    unsigned u = __float_as_uint(f);
    u += 0x7FFFu + ((u >> 16) & 1u);          // RNE to bf16
    return (unsigned short)(u >> 16);
}

// one instruction packs two fp32 -> two bf16 (dst.lo = src0, dst.hi = src1)
__device__ __forceinline__ unsigned cvt_pk_bf16(float lo, float hi) {
    unsigned r;
    asm("v_cvt_pk_bf16_f32 %0, %1, %2" : "=v"(r) : "v"(lo), "v"(hi));
    return r;
}

// gelu_tanh(v) = v * sigmoid(2*c0*(v + c1 v^3)), vectorized 2-wide so the
// compiler emits packed v_pk_{mul,fma,add}_f32. Only exp/rcp are scalar trans.
__device__ __forceinline__ f32x2 fast_gelu2(f32x2 v) {
    const f32x2 c1v  = {0.044715f, 0.044715f};
    const f32x2 onev = {1.0f, 1.0f};
    const f32x2 K2v  = {-2.3022081951f, -2.3022081951f};  // -2*sqrt(2/pi)*log2(e)
    f32x2 p = v * __builtin_elementwise_fma(c1v, v * v, onev);
    f32x2 t = K2v * p;
    float e0, e1, r0, r1;
    asm("v_exp_f32 %0, %1" : "=v"(e0) : "v"(t.x));
    asm("v_exp_f32 %0, %1" : "=v"(e1) : "v"(t.y));
    f32x2 ev = {e0, e1};
    f32x2 d = ev + onev;
    asm("v_rcp_f32 %0, %1" : "=v"(r0) : "v"(d.x));
    asm("v_rcp_f32 %0, %1" : "=v"(r1) : "v"(d.y));
    f32x2 rv = {r0, r1};
    return v * rv;
}

// k-SLOT REMAP (slot = MFMA contraction index, logical = reference k):
//   slot 0..63  -> edge_in logical k = slot+6   (f_y[0..63], 16B-aligned gathers)
//   slot 64..69 -> edge_in logical k = slot-64  (y0 y1 y2 x0 x1 x2)
//   slot 70..95 -> zero pad
__global__ __launch_bounds__(256) void pack_weights_kernel(
    const float* __restrict__ W1, const float* __restrict__ W2,
    int4* __restrict__ W1p, int4* __restrict__ W2p)
{
    const int idx = blockIdx.x * 256 + threadIdx.x;
    unsigned short vals[8];
    if (idx < 1536) {                      // 24 regions x 64 lanes
        const int r = idx >> 6, lane = idx & 63;
        const int mt = r / 3, s = r - mt * 3;
        const int row = mt * 16 + (lane & 15), g = lane >> 4;
        #pragma unroll
        for (int e = 0; e < 8; ++e) {
            const int k = s * 32 + g * 8 + e;          // slot index
            float f;
            if      (k < 64) f = W1[(k + 6) * 128 + row];   // f_y features
            else if (k < 70) f = W1[(k - 64) * 128 + row];  // y,x coords
            else             f = 0.0f;
            vals[e] = f2bf(f);
        }
        int4 v;
        v.x = vals[0] | (vals[1] << 16); v.y = vals[2] | (vals[3] << 16);
        v.z = vals[4] | (vals[5] << 16); v.w = vals[6] | (vals[7] << 16);
        W1p[idx] = v;
    } else if (idx < 2560) {               // 16 regions x 64 lanes
        const int i2 = idx - 1536;
        const int r = i2 >> 6, lane = i2 & 63;
        const int s = r >> 2, nt = r & 3;
        const int col = nt * 16 + (lane & 15), g = lane >> 4;
        #pragma unroll
        for (int e = 0; e < 8; ++e) {
            const int k = s * 32 + g * 4 + (e & 3) + 16 * (e >> 2);
            vals[e] = f2bf(W2[k * 64 + col]);
        }
        int4 v;
        v.x = vals[0] | (vals[1] << 16); v.y = vals[2] | (vals[3] << 16);
        v.z = vals[4] | (vals[5] << 16); v.w = vals[6] | (vals[7] << 16);
        W2p[i2] = v;
    }
}

// full per-query compute: GEMM1 + gelu + softmax + GEMM2 + weighted reduce
__device__ __forceinline__ void process_query(
    int q, const Frag (&B1)[2][3],
    const int4* __restrict__ sW1, const int4* __restrict__ sW2,
    const float* __restrict__ b1, const float* __restrict__ av,
    const float* __restrict__ b2, float* __restrict__ out,
    int l, int g)
{
    const f32x4 zero4 = {0.f, 0.f, 0.f, 0.f};

    Frag A2[2][4];                     // [nt][s2]  h as GEMM2 A-fragments
    f32x2 sc0v = {0.f, 0.f}, sc1v = {0.f, 0.f};
    #pragma unroll
    for (int j = 0; j < 4; ++j) {      // mt pair (2j, 2j+1)
        f32x4 acc[2][2] = {{zero4, zero4}, {zero4, zero4}};  // [mp][nt]
        #pragma unroll
        for (int s = 0; s < 3; ++s) {
            Frag wa0, wa1;
            wa0.i = sW1[((2 * j + 0) * 3 + s) * 64 + l];
            wa1.i = sW1[((2 * j + 1) * 3 + s) * 64 + l];
            acc[0][0] = __builtin_amdgcn_mfma_f32_16x16x32_bf16(wa0.b, B1[0][s].b, acc[0][0], 0, 0, 0);
            acc[0][1] = __builtin_amdgcn_mfma_f32_16x16x32_bf16(wa0.b, B1[1][s].b, acc[0][1], 0, 0, 0);
            acc[1][0] = __builtin_amdgcn_mfma_f32_16x16x32_bf16(wa1.b, B1[0][s].b, acc[1][0], 0, 0, 0);
            acc[1][1] = __builtin_amdgcn_mfma_f32_16x16x32_bf16(wa1.b, B1[1][s].b, acc[1][1], 0, 0, 0);
        }
        #pragma unroll
        for (int mp = 0; mp < 2; ++mp) {
            const int hbase = (2 * j + mp) * 16 + g * 4;
            float4 b14 = *(const float4*)(b1 + hbase);
            float4 a14 = *(const float4*)(av + hbase);
            f32x2 b01 = {b14.x, b14.y}, b23 = {b14.z, b14.w};
            f32x2 a01 = {a14.x, a14.y}, a23 = {a14.z, a14.w};

            f32x2 t0a = {acc[mp][0][0], acc[mp][0][1]};
            f32x2 t0b = {acc[mp][0][2], acc[mp][0][3]};
            f32x2 t1a = {acc[mp][1][0], acc[mp][1][1]};
            f32x2 t1b = {acc[mp][1][2], acc[mp][1][3]};
            f32x2 h0a = fast_gelu2(t0a + b01);
            f32x2 h0b = fast_gelu2(t0b + b23);
            f32x2 h1a = fast_gelu2(t1a + b01);
            f32x2 h1b = fast_gelu2(t1b + b23);

            sc0v = __builtin_elementwise_fma(h0a, a01, sc0v);
            sc0v = __builtin_elementwise_fma(h0b, a23, sc0v);
            sc1v = __builtin_elementwise_fma(h1a, a01, sc1v);
            sc1v = __builtin_elementwise_fma(h1b, a23, sc1v);

            if (mp == 0) {
                A2[0][j].i.x = cvt_pk_bf16(h0a.x, h0a.y);
                A2[0][j].i.y = cvt_pk_bf16(h0b.x, h0b.y);
                A2[1][j].i.x = cvt_pk_bf16(h1a.x, h1a.y);
                A2[1][j].i.y = cvt_pk_bf16(h1b.x, h1b.y);
            } else {
                A2[0][j].i.z = cvt_pk_bf16(h0a.x, h0a.y);
                A2[0][j].i.w = cvt_pk_bf16(h0b.x, h0b.y);
                A2[1][j].i.z = cvt_pk_bf16(h1a.x, h1a.y);
                A2[1][j].i.w = cvt_pk_bf16(h1b.x, h1b.y);
            }
        }
    }
    float sc0 = sc0v.x + sc0v.y;
    float sc1 = sc1v.x + sc1v.y;

    // in-wave softmax over 32 edges
    sc0 += __shfl_xor(sc0, 16, 64); sc0 += __shfl_xor(sc0, 32, 64);
    sc1 += __shfl_xor(sc1, 16, 64); sc1 += __shfl_xor(sc1, 32, 64);
    float mx = fmaxf(sc0, sc1);
    mx = fmaxf(mx, __shfl_xor(mx, 1, 64));
    mx = fmaxf(mx, __shfl_xor(mx, 2, 64));
    mx = fmaxf(mx, __shfl_xor(mx, 4, 64));
    mx = fmaxf(mx, __shfl_xor(mx, 8, 64));
    float ex0 = __expf(sc0 - mx);
    float ex1 = __expf(sc1 - mx);
    float sm = ex0 + ex1;
    sm += __shfl_xor(sm, 1, 64);
    sm += __shfl_xor(sm, 2, 64);
    sm += __shfl_xor(sm, 4, 64);
    sm += __shfl_xor(sm, 8, 64);
    const float inv = __fdividef(1.0f, sm);
    const float al0 = ex0 * inv;
    const float al1 = ex1 * inv;

    // GEMM2 (W2 frags from LDS)
    f32x4 acc2[2][4] = {{zero4, zero4, zero4, zero4},
                        {zero4, zero4, zero4, zero4}};
    #pragma unroll
    for (int s2 = 0; s2 < 4; ++s2) {
        #pragma unroll
        for (int nto = 0; nto < 4; ++nto) {
            Frag wb;
            wb.i = sW2[(s2 * 4 + nto) * 64 + l];
            acc2[0][nto] = __builtin_amdgcn_mfma_f32_16x16x32_bf16(A2[0][s2].b, wb.b, acc2[0][nto], 0, 0, 0);
            acc2[1][nto] = __builtin_amdgcn_mfma_f32_16x16x32_bf16(A2[1][s2].b, wb.b, acc2[1][nto], 0, 0, 0);
        }
    }

    // alpha-weighted edge reduce (packed fp32) + store
    f32x2 ar0a, ar0b, ar1a, ar1b;
    ar0a.x = __shfl(al0, g * 4 + 0, 64); ar0a.y = __shfl(al0, g * 4 + 1, 64);
    ar0b.x = __shfl(al0, g * 4 + 2, 64); ar0b.y = __shfl(al0, g * 4 + 3, 64);
    ar1a.x = __shfl(al1, g * 4 + 0, 64); ar1a.y = __shfl(al1, g * 4 + 1, 64);
    ar1b.x = __shfl(al1, g * 4 + 2, 64); ar1b.y = __shfl(al1, g * 4 + 3, 64);
    #pragma unroll
    for (int nto = 0; nto < 4; ++nto) {
        f32x2 p0 = {acc2[0][nto][0], acc2[0][nto][1]};
        f32x2 p1 = {acc2[0][nto][2], acc2[0][nto][3]};
        f32x2 p2 = {acc2[1][nto][0], acc2[1][nto][1]};
        f32x2 p3 = {acc2[1][nto][2], acc2[1][nto][3]};
        f32x2 o2 = p0 * ar0a;
        o2 = __builtin_elementwise_fma(p1, ar0b, o2);
        o2 = __builtin_elementwise_fma(p2, ar1a, o2);
        o2 = __builtin_elementwise_fma(p3, ar1b, o2);
        float o = o2.x + o2.y;
        o += __shfl_xor(o, 16, 64);
        o += __shfl_xor(o, 32, 64);
        if (l < 16)
            out[q * 64 + nto * 16 + l] = o + b2[nto * 16 + l];
    }
}

__global__ __launch_bounds__(512, 4) void it_mfma_kernel(
    const float* __restrict__ y,     // [n_in][3]
    const float* __restrict__ xq,    // [n_out][3]
    const float* __restrict__ f_y,   // [n_in][64]
    const float* __restrict__ b1,    // [128]
    const float* __restrict__ b2,    // [64]
    const float* __restrict__ av,    // [128]
    const int*   __restrict__ nbr,   // [n_out*32]
    const int4*  __restrict__ Wall,  // W1p (1536) ++ W2p (1024) fragments
    float*       __restrict__ out,   // [n_out][64]
    int n_out)
{
    __shared__ int4 sW[2560];              // 40 KB: W1 frags then W2 frags

    const int tid = threadIdx.x;
    const int w   = tid >> 6;              // wave 0..7
    const int l   = tid & 63;              // lane
    const int l15 = l & 15;
    const int g   = l >> 4;                // quarter-group 0..3

    const int qbase = (blockIdx.x * WAVES + w) * GQ;
    const int qc0 = (qbase     < n_out) ? qbase     : 0;
    const int qc1 = (qbase + 1 < n_out) ? qbase + 1 : qc0;

    // ---- all nbr loads issue first: overlap with staging + barrier ----
    const int ni0a = nbr[qc0 * KNBR + l15];
    const int ni1a = nbr[qc0 * KNBR + 16 + l15];
    const int ni0b = nbr[qc1 * KNBR + l15];
    const int ni1b = nbr[qc1 * KNBR + 16 + l15];

    // ---- prologue (only barrier): stage packed weights into LDS ----
    #pragma unroll
    for (int t = 0; t < 5; ++t)
        sW[tid + t * 512] = Wall[tid + t * 512];
    __syncthreads();
    const int4* sW1 = sW;                  // region (mt*3+s)*64 + lane
    const int4* sW2 = sW + 1536;           // region (s2*4+nto)*64 + lane

    if (qbase >= n_out) return;            // after the only barrier: safe

    // ---- issue query-0 f_y gathers ----
    const float4* fa0 = (const float4*)(f_y + (long)ni0a * 64 + g * 8);
    const float4* fa1 = (const float4*)(f_y + (long)ni1a * 64 + g * 8);
    float4 a0 = fa0[0], a1 = fa0[1], a2 = fa0[8], a3 = fa0[9];
    float4 c0 = fa1[0], c1 = fa1[1], c2 = fa1[8], c3 = fa1[9];

    // ---- issue query-1 f_y gathers: stay in flight across query-0 compute --
    const float4* fb0 = (const float4*)(f_y + (long)ni0b * 64 + g * 8);
    const float4* fb1 = (const float4*)(f_y + (long)ni1b * 64 + g * 8);
    float4 d0 = fb0[0], d1 = fb0[1], d2 = fb0[8], d3 = fb0[9];
    float4 e0 = fb1[0], e1 = fb1[1], e2 = fb1[8], e3 = fb1[9];

    // ---- build B1 (query 0): counted vmcnt waits on a*/c* only ----
    Frag B1[2][3];
    B1[0][0].i.x = cvt_pk_bf16(a0.x, a0.y);
    B1[0][0].i.y = cvt_pk_bf16(a0.z, a0.w);
    B1[0][0].i.z = cvt_pk_bf16(a1.x, a1.y);
    B1[0][0].i.w = cvt_pk_bf16(a1.z, a1.w);
    B1[0][1].i.x = cvt_pk_bf16(a2.x, a2.y);
    B1[0][1].i.y = cvt_pk_bf16(a2.z, a2.w);
    B1[0][1].i.z = cvt_pk_bf16(a3.x, a3.y);
    B1[0][1].i.w = cvt_pk_bf16(a3.z, a3.w);
    B1[1][0].i.x = cvt_pk_bf16(c0.x, c0.y);
    B1[1][0].i.y = cvt_pk_bf16(c0.z, c0.w);
    B1[1][0].i.z = cvt_pk_bf16(c1.x, c1.y);
    B1[1][0].i.w = cvt_pk_bf16(c1.z, c1.w);
    B1[1][1].i.x = cvt_pk_bf16(c2.x, c2.y);
    B1[1][1].i.y = cvt_pk_bf16(c2.z, c2.w);
    B1[1][1].i.z = cvt_pk_bf16(c3.x, c3.y);
    B1[1][1].i.w = cvt_pk_bf16(c3.z, c3.w);
    B1[0][2].i = make_int4(0, 0, 0, 0);
    B1[1][2].i = make_int4(0, 0, 0, 0);
    if (g == 0) {
        float2 ya = *(const float2*)(y + ni0a * 3);
        float  yaz = y[ni0a * 3 + 2];
        float2 yb = *(const float2*)(y + ni1a * 3);
        float  ybz = y[ni1a * 3 + 2];
        float2 x01 = *(const float2*)(xq + qc0 * 3);
        float  xz  = xq[qc0 * 3 + 2];
        B1[0][2].i.x = cvt_pk_bf16(ya.x, ya.y);
        B1[0][2].i.y = cvt_pk_bf16(yaz,  x01.x);
        B1[0][2].i.z = cvt_pk_bf16(x01.y, xz);
        B1[1][2].i.x = cvt_pk_bf16(yb.x, yb.y);
        B1[1][2].i.y = cvt_pk_bf16(ybz,  x01.x);
        B1[1][2].i.z = cvt_pk_bf16(x01.y, xz);
    }

    // ---- query 0: compute (query-1 loads land underneath) ----
    process_query(qc0, B1, sW1, sW2, b1, av, b2, out, l, g);

    if (qbase + 1 >= n_out) return;

    // ---- build B1 (query 1): loads already landed, no stall ----
    Frag B1b[2][3];
    B1b[0][0].i.x = cvt_pk_bf16(d0.x, d0.y);
    B1b[0][0].i.y = cvt_pk_bf16(d0.z, d0.w);
    B1b[0][0].i.z = cvt_pk_bf16(d1.x, d1.y);
    B1b[0][0].i.w = cvt_pk_bf16(d1.z, d1.w);
    B1b[0][1].i.x = cvt_pk_bf16(d2.x, d2.y);
    B1b[0][1].i.y = cvt_pk_bf16(d2.z, d2.w);
    B1b[0][1].i.z = cvt_pk_bf16(d3.x, d3.y);
    B1b[0][1].i.w = cvt_pk_bf16(d3.z, d3.w);
    B1b[1][0].i.x = cvt_pk_bf16(e0.x, e0.y);
    B1b[1][0].i.y = cvt_pk_bf16(e0.z, e0.w);
    B1b[1][0].i.z = cvt_pk_bf16(e1.x, e1.y);
    B1b[1][0].i.w = cvt_pk_bf16(e1.z, e1.w);
    B1b[1][1].i.x = cvt_pk_bf16(e2.x, e2.y);
    B1b[1][1].i.y = cvt_pk_bf16(e2.z, e2.w);
    B1b[1][1].i.z = cvt_pk_bf16(e3.x, e3.y);
    B1b[1][1].i.w = cvt_pk_bf16(e3.z, e3.w);
    B1b[0][2].i = make_int4(0, 0, 0, 0);
    B1b[1][2].i = make_int4(0, 0, 0, 0);
    if (g == 0) {
        float2 ya = *(const float2*)(y + ni0b * 3);
        float  yaz = y[ni0b * 3 + 2];
        float2 yb = *(const float2*)(y + ni1b * 3);
        float  ybz = y[ni1b * 3 + 2];
        float2 x01 = *(const float2*)(xq + qc1 * 3);
        float  xz  = xq[qc1 * 3 + 2];
        B1b[0][2].i.x = cvt_pk_bf16(ya.x, ya.y);
        B1b[0][2].i.y = cvt_pk_bf16(yaz,  x01.x);
        B1b[0][2].i.z = cvt_pk_bf16(x01.y, xz);
        B1b[1][2].i.x = cvt_pk_bf16(yb.x, yb.y);
        B1b[1][2].i.y = cvt_pk_bf16(ybz,  x01.x);
        B1b[1][2].i.z = cvt_pk_bf16(x01.y, xz);
    }

    // ---- query 1: compute ----
    process_query(qc1, B1b, sW1, sW2, b1, av, b2, out, l, g);
}

extern "C" void kernel_launch(void* const* d_in, const int* in_sizes, int n_in,
                              void* d_out, int out_size, void* d_ws, size_t ws_size,
                              hipStream_t stream) {
    const float* y   = (const float*)d_in[0];
    const float* xq  = (const float*)d_in[1];
    const float* f_y = (const float*)d_in[2];
    const float* W1  = (const float*)d_in[3];
    const float* b1  = (const float*)d_in[4];
    const float* W2  = (const float*)d_in[5];
    const float* b2  = (const float*)d_in[6];
    const float* av  = (const float*)d_in[7];
    const int*   nbr = (const int*)d_in[8];
    float* out = (float*)d_out;

    const int n_out = in_sizes[1] / 3;      // x is [n_out][3]

    int4* W1p = (int4*)d_ws;                // 1536 frags = 24 KB
    int4* W2p = W1p + 1536;                 // 1024 frags = 16 KB (contiguous)

    pack_weights_kernel<<<10, 256, 0, stream>>>(W1, W2, W1p, W2p);
    const int qpb = WAVES * GQ;             // 16 queries per block
    const int nblk = (n_out + qpb - 1) / qpb;
    it_mfma_kernel<<<nblk, 512, 0, stream>>>(y, xq, f_y, b1, b2, av, nbr,
                                             W1p, out, n_out);
}

// Round 15
// 72.051 us; speedup vs baseline: 4.7291x; 4.7291x over previous
//
#include <hip/hip_runtime.h>

typedef __attribute__((ext_vector_type(8)))  short bf16x8;
typedef __attribute__((ext_vector_type(16))) float f32x16;
typedef __attribute__((ext_vector_type(2)))  float f32x2;

#define KNBR 32
#define WAVES 8         // waves per block, one query per wave (512 threads)

union Frag { int4 i; bf16x8 b; };

__device__ __forceinline__ unsigned short f2bf(float f) {
    unsigned u = __float_as_uint(f);
    u += 0x7FFFu + ((u >> 16) & 1u);          // RNE to bf16
    return (unsigned short)(u >> 16);
}

__device__ __forceinline__ unsigned cvt_pk_bf16(float lo, float hi) {
    unsigned r;
    asm("v_cvt_pk_bf16_f32 %0, %1, %2" : "=v"(r) : "v"(lo), "v"(hi));
    return r;
}

// gelu_tanh(v) = v * sigmoid(2*c0*(v + c1 v^3)); exp via v_exp_f32 (2^x).
__device__ __forceinline__ float fast_gelu(float v) {
    const float c1 = 0.044715f;
    const float K2 = -2.3022081951f;          // -2*sqrt(2/pi)*log2(e)
    float p = v * fmaf(c1, v * v, 1.0f);
    float e, r;
    asm("v_exp_f32 %0, %1" : "=v"(e) : "v"(K2 * p));
    float d = 1.0f + e;
    asm("v_rcp_f32 %0, %1" : "=v"(r) : "v"(d));
    return v * r;
}

// 32x32x16 fragment maps (A: row=l&31, B: col=l&31, k=(l>>5)*8+e per K-step).
// C/D: col=lane&31, row=(reg&3)+8*(reg>>2)+4*(lane>>5)  [verified m74/m101].
//
// GEMM1 slot map (K padded 70->80, 5 K-steps):
//   slot 0..63 -> f_y col slot; 64..69 -> y0 y1 y2 x0 x1 x2; 70 -> BIAS (edge
//   value 1.0, weight b1[row]); 71..79 -> zero.
// GEMM2 slot map matches h's C/D register layout identically:
//   frag ks2, lane-half hi, elem e  <->  hidden = (ks2>>1)*32
//       + 4*(2*(2*(ks2&1)+(e>>2)) + hi) ... i.e. A2[2*Mt] = h regs 0..7,
//   A2[2*Mt+1] = h regs 8..15 (identity packing).
__global__ __launch_bounds__(256) void pack_weights_kernel(
    const float* __restrict__ W1, const float* __restrict__ W2,
    const float* __restrict__ b1, const float* __restrict__ av,
    int4* __restrict__ W1p, int4* __restrict__ W2p, float* __restrict__ avp)
{
    const int idx = blockIdx.x * 256 + threadIdx.x;
    unsigned short vals[8];
    if (idx < 1280) {                      // W1 A-frags: 20 regions x 64 lanes
        const int a = idx >> 6, l = idx & 63;
        const int Mt = a / 5, ks = a - Mt * 5;
        const int row = Mt * 32 + (l & 31), hi = l >> 5;
        #pragma unroll
        for (int e = 0; e < 8; ++e) {
            const int slot = ks * 16 + hi * 8 + e;
            float f;
            if      (slot < 64)  f = W1[(slot + 6) * 128 + row];
            else if (slot < 70)  f = W1[(slot - 64) * 128 + row];
            else if (slot == 70) f = b1[row];
            else                 f = 0.0f;
            vals[e] = f2bf(f);
        }
        int4 v;
        v.x = vals[0] | (vals[1] << 16); v.y = vals[2] | (vals[3] << 16);
        v.z = vals[4] | (vals[5] << 16); v.w = vals[6] | (vals[7] << 16);
        W1p[idx] = v;
    } else if (idx < 2304) {               // W2 B-frags: 16 regions x 64 lanes
        const int i2 = idx - 1280;
        const int rgn = i2 >> 6, l = i2 & 63;
        const int Nt = rgn >> 3, ks2 = rgn & 7;
        const int col = Nt * 32 + (l & 31), hi = l >> 5;
        #pragma unroll
        for (int e = 0; e < 8; ++e) {
            const int Mt = ks2 >> 1;
            const int t  = 2 * (ks2 & 1) + (e >> 2);
            const int c  = e & 3;
            const int hid = Mt * 32 + 4 * (2 * t + hi) + c;
            vals[e] = f2bf(W2[hid * 64 + col]);
        }
        int4 v;
        v.x = vals[0] | (vals[1] << 16); v.y = vals[2] | (vals[3] << 16);
        v.z = vals[4] | (vals[5] << 16); v.w = vals[6] | (vals[7] << 16);
        W2p[i2] = v;
    } else if (idx < 2432) {               // av repacked into C/D reg order
        const int r_ = idx - 2304;         // [Mt][hi][r]
        const int Mt = r_ >> 5, hi = (r_ >> 4) & 1, r = r_ & 15;
        avp[r_] = av[Mt * 32 + 8 * (r >> 2) + 4 * hi + (r & 3)];
    }
}

__global__ __launch_bounds__(512, 4) void it_mfma_kernel(
    const float* __restrict__ y,     // [n_in][3]
    const float* __restrict__ xq,    // [n_out][3]
    const float* __restrict__ f_y,   // [n_in][64]
    const float* __restrict__ b2,    // [64]
    const int*   __restrict__ nbr,   // [n_out*32]
    const int4*  __restrict__ Wall,  // W1p(1280) ++ W2p(1024) ++ avp(128 f32)
    float*       __restrict__ out,   // [n_out][64]
    int n_out)
{
    __shared__ int4  sW[2304];             // 36 KB: W1 frags then W2 frags
    __shared__ float sAv[128];             // av in C/D register order

    const int tid = threadIdx.x;
    const int w   = tid >> 6;              // wave 0..7
    const int l   = tid & 63;              // lane
    const int el  = l & 31;                // this lane's edge
    const int hi  = l >> 5;                // lane half

    const int q = blockIdx.x * WAVES + w;
    const bool active = (q < n_out);
    const int qc = active ? q : 0;

    // nbr early (dependent f_y chain starts during staging)
    const int ni = active ? nbr[qc * KNBR + el] : 0;

    // ---- prologue (only barrier): stage fragments + av into LDS ----
    #pragma unroll
    for (int t = 0; t < 5; ++t) {
        const int idx = tid + t * 512;
        if (idx < 2304) sW[idx] = Wall[idx];
    }
    if (tid < 128) sAv[tid] = ((const float*)(Wall + 2304))[tid];
    __syncthreads();
    const int4* sW1 = sW;                  // region (Mt*5+ks)*64 + lane
    const int4* sW2 = sW + 1280;           // region (Nt*8+ks2)*64 + lane

    if (!active) return;

    // ---------- phase 1: gather edge el into B1 fragments ----------
    const float4* fb = (const float4*)(f_y + (long)ni * 64);
    float4 u0 = fb[ 0 + 2 * hi], u1 = fb[ 1 + 2 * hi];
    float4 u2 = fb[ 4 + 2 * hi], u3 = fb[ 5 + 2 * hi];
    float4 u4 = fb[ 8 + 2 * hi], u5 = fb[ 9 + 2 * hi];
    float4 u6 = fb[12 + 2 * hi], u7 = fb[13 + 2 * hi];

    Frag B1[5];
    B1[0].i.x = cvt_pk_bf16(u0.x, u0.y); B1[0].i.y = cvt_pk_bf16(u0.z, u0.w);
    B1[0].i.z = cvt_pk_bf16(u1.x, u1.y); B1[0].i.w = cvt_pk_bf16(u1.z, u1.w);
    B1[1].i.x = cvt_pk_bf16(u2.x, u2.y); B1[1].i.y = cvt_pk_bf16(u2.z, u2.w);
    B1[1].i.z = cvt_pk_bf16(u3.x, u3.y); B1[1].i.w = cvt_pk_bf16(u3.z, u3.w);
    B1[2].i.x = cvt_pk_bf16(u4.x, u4.y); B1[2].i.y = cvt_pk_bf16(u4.z, u4.w);
    B1[2].i.z = cvt_pk_bf16(u5.x, u5.y); B1[2].i.w = cvt_pk_bf16(u5.z, u5.w);
    B1[3].i.x = cvt_pk_bf16(u6.x, u6.y); B1[3].i.y = cvt_pk_bf16(u6.z, u6.w);
    B1[3].i.z = cvt_pk_bf16(u7.x, u7.y); B1[3].i.w = cvt_pk_bf16(u7.z, u7.w);
    B1[4].i = make_int4(0, 0, 0, 0);
    if (hi == 0) {                         // slots 64..71: coords + bias-1.0
        float2 y01 = *(const float2*)(y + ni * 3);
        float  yz  = y[ni * 3 + 2];
        float2 x01 = *(const float2*)(xq + qc * 3);
        float  xz  = xq[qc * 3 + 2];
        B1[4].i.x = cvt_pk_bf16(y01.x, y01.y);
        B1[4].i.y = cvt_pk_bf16(yz,    x01.x);
        B1[4].i.z = cvt_pk_bf16(x01.y, xz);
        B1[4].i.w = cvt_pk_bf16(1.0f,  0.0f);   // slot 70 = bias edge value
    }

    const f32x16 z16 = {0.f,0.f,0.f,0.f,0.f,0.f,0.f,0.f,
                        0.f,0.f,0.f,0.f,0.f,0.f,0.f,0.f};

    // ---------- phase 2+3: GEMM1 (Mtile pairs) + gelu + score + A2 ----------
    Frag A2[8];
    f32x2 scv = {0.f, 0.f};
    #pragma unroll
    for (int p = 0; p < 2; ++p) {
        f32x16 aA = z16, aB = z16;
        #pragma unroll
        for (int ks = 0; ks < 5; ++ks) {
            Frag wa0, wa1;
            wa0.i = sW1[((2 * p + 0) * 5 + ks) * 64 + l];
            wa1.i = sW1[((2 * p + 1) * 5 + ks) * 64 + l];
            aA = __builtin_amdgcn_mfma_f32_32x32x16_bf16(wa0.b, B1[ks].b, aA, 0, 0, 0);
            aB = __builtin_amdgcn_mfma_f32_32x32x16_bf16(wa1.b, B1[ks].b, aB, 0, 0, 0);
        }
        #pragma unroll
        for (int m = 0; m < 2; ++m) {
            const f32x16 ac = m ? aB : aA;
            const int Mt = 2 * p + m;
            const float* avb = sAv + Mt * 32 + hi * 16;
            float4 av0 = *(const float4*)(avb + 0);
            float4 av1 = *(const float4*)(avb + 4);
            float4 av2 = *(const float4*)(avb + 8);
            float4 av3 = *(const float4*)(avb + 12);
            float avr[16] = {av0.x, av0.y, av0.z, av0.w,
                             av1.x, av1.y, av1.z, av1.w,
                             av2.x, av2.y, av2.z, av2.w,
                             av3.x, av3.y, av3.z, av3.w};
            float h[16];
            #pragma unroll
            for (int r = 0; r < 16; ++r) h[r] = fast_gelu(ac[r]);
            #pragma unroll
            for (int i = 0; i < 8; ++i) {
                f32x2 hv = {h[2 * i], h[2 * i + 1]};
                f32x2 avv = {avr[2 * i], avr[2 * i + 1]};
                scv = __builtin_elementwise_fma(hv, avv, scv);
            }
            A2[2 * Mt + 0].i.x = cvt_pk_bf16(h[0],  h[1]);
            A2[2 * Mt + 0].i.y = cvt_pk_bf16(h[2],  h[3]);
            A2[2 * Mt + 0].i.z = cvt_pk_bf16(h[4],  h[5]);
            A2[2 * Mt + 0].i.w = cvt_pk_bf16(h[6],  h[7]);
            A2[2 * Mt + 1].i.x = cvt_pk_bf16(h[8],  h[9]);
            A2[2 * Mt + 1].i.y = cvt_pk_bf16(h[10], h[11]);
            A2[2 * Mt + 1].i.z = cvt_pk_bf16(h[12], h[13]);
            A2[2 * Mt + 1].i.w = cvt_pk_bf16(h[14], h[15]);
        }
    }

    // ---------- phase 4: softmax (edge el per lane) ----------
    float sc = scv.x + scv.y;
    sc += __shfl_xor(sc, 32, 64);          // sum over lane halves (hidden split)
    float mx = sc;
    mx = fmaxf(mx, __shfl_xor(mx, 1, 64));
    mx = fmaxf(mx, __shfl_xor(mx, 2, 64));
    mx = fmaxf(mx, __shfl_xor(mx, 4, 64));
    mx = fmaxf(mx, __shfl_xor(mx, 8, 64));
    mx = fmaxf(mx, __shfl_xor(mx, 16, 64));
    float ex = __expf(sc - mx);
    float sm = ex;
    sm += __shfl_xor(sm, 1, 64);
    sm += __shfl_xor(sm, 2, 64);
    sm += __shfl_xor(sm, 4, 64);
    sm += __shfl_xor(sm, 8, 64);
    sm += __shfl_xor(sm, 16, 64);
    const float alpha = __fdividef(ex, sm);    // alpha[edge el]

    // ---------- phase 5: GEMM2 (D[edge][out], K=128 over 8 steps) ----------
    f32x16 o0 = z16, o1 = z16;
    #pragma unroll
    for (int ks2 = 0; ks2 < 8; ++ks2) {
        Frag w0, w1;
        w0.i = sW2[(0 * 8 + ks2) * 64 + l];
        w1.i = sW2[(1 * 8 + ks2) * 64 + l];
        o0 = __builtin_amdgcn_mfma_f32_32x32x16_bf16(A2[ks2].b, w0.b, o0, 0, 0, 0);
        o1 = __builtin_amdgcn_mfma_f32_32x32x16_bf16(A2[ks2].b, w1.b, o1, 0, 0, 0);
    }

    // ---------- phase 6: alpha-weighted edge reduce + store ----------
    float ar[16];
    #pragma unroll
    for (int r = 0; r < 16; ++r)
        ar[r] = __shfl(alpha, 8 * (r >> 2) + 4 * hi + (r & 3), 64);

    #pragma unroll
    for (int nt = 0; nt < 2; ++nt) {
        const f32x16 oo = nt ? o1 : o0;
        f32x2 acc = {0.f, 0.f};
        #pragma unroll
        for (int i = 0; i < 8; ++i) {
            f32x2 ov = {oo[2 * i], oo[2 * i + 1]};
            f32x2 av2 = {ar[2 * i], ar[2 * i + 1]};
            acc = __builtin_elementwise_fma(ov, av2, acc);
        }
        float o = acc.x + acc.y;
        o += __shfl_xor(o, 32, 64);        // sum the two lane halves' edges
        if (l < 32)
            out[qc * 64 + nt * 32 + l] = o + b2[nt * 32 + l];
    }
}

extern "C" void kernel_launch(void* const* d_in, const int* in_sizes, int n_in,
                              void* d_out, int out_size, void* d_ws, size_t ws_size,
                              hipStream_t stream) {
    const float* y   = (const float*)d_in[0];
    const float* xq  = (const float*)d_in[1];
    const float* f_y = (const float*)d_in[2];
    const float* W1  = (const float*)d_in[3];
    const float* b1  = (const float*)d_in[4];
    const float* W2  = (const float*)d_in[5];
    const float* b2  = (const float*)d_in[6];
    const float* av  = (const float*)d_in[7];
    const int*   nbr = (const int*)d_in[8];
    float* out = (float*)d_out;

    const int n_out = in_sizes[1] / 3;      // x is [n_out][3]

    int4*  W1p = (int4*)d_ws;               // 1280 frags = 20 KB
    int4*  W2p = W1p + 1280;                // 1024 frags = 16 KB
    float* avp = (float*)(W1p + 2304);      // 128 floats

    pack_weights_kernel<<<10, 256, 0, stream>>>(W1, W2, b1, av, W1p, W2p, avp);
    const int nblk = (n_out + WAVES - 1) / WAVES;
    it_mfma_kernel<<<nblk, 512, 0, stream>>>(y, xq, f_y, b2, nbr,
                                             W1p, out, n_out);
}

// Round 16
// 71.421 us; speedup vs baseline: 4.7709x; 1.0088x over previous
//
#include <hip/hip_runtime.h>

typedef __attribute__((ext_vector_type(8)))  short bf16x8;
typedef __attribute__((ext_vector_type(16))) float f32x16;
typedef __attribute__((ext_vector_type(2)))  float f32x2;

#define KNBR 32
#define WAVES 8         // waves per block, one query per wave (512 threads)

union Frag { int4 i; bf16x8 b; };

__device__ __forceinline__ unsigned short f2bf(float f) {
    unsigned u = __float_as_uint(f);
    u += 0x7FFFu + ((u >> 16) & 1u);          // RNE to bf16
    return (unsigned short)(u >> 16);
}

__device__ __forceinline__ unsigned cvt_pk_bf16(float lo, float hi) {
    unsigned r;
    asm("v_cvt_pk_bf16_f32 %0, %1, %2" : "=v"(r) : "v"(lo), "v"(hi));
    return r;
}

// gelu_tanh(v) = v * sigmoid(2*c0*(v + c1 v^3)), 2-wide packed so the compiler
// emits v_pk_{mul,fma,add}_f32; only exp/rcp are scalar trans ops.
__device__ __forceinline__ f32x2 fast_gelu2(f32x2 v) {
    const f32x2 c1v  = {0.044715f, 0.044715f};
    const f32x2 onev = {1.0f, 1.0f};
    const f32x2 K2v  = {-2.3022081951f, -2.3022081951f};  // -2*sqrt(2/pi)*log2(e)
    f32x2 p = v * __builtin_elementwise_fma(c1v, v * v, onev);
    f32x2 t = K2v * p;
    float e0, e1, r0, r1;
    asm("v_exp_f32 %0, %1" : "=v"(e0) : "v"(t.x));
    asm("v_exp_f32 %0, %1" : "=v"(e1) : "v"(t.y));
    f32x2 ev = {e0, e1};
    f32x2 d = ev + onev;
    asm("v_rcp_f32 %0, %1" : "=v"(r0) : "v"(d.x));
    asm("v_rcp_f32 %0, %1" : "=v"(r1) : "v"(d.y));
    f32x2 rv = {r0, r1};
    return v * rv;
}

// 32x32x16 fragment maps (A: row=l&31, B: col=l&31, k=(l>>5)*8+e per K-step).
// C/D: col=lane&31, row=(reg&3)+8*(reg>>2)+4*(lane>>5)  [verified m74/m101].
//
// GEMM1 slot map (K padded 70->80, 5 K-steps):
//   slot 0..63 -> f_y col slot; 64..69 -> y0 y1 y2 x0 x1 x2; 70 -> BIAS (edge
//   value 1.0, weight b1[row]); 71..79 -> zero.
// GEMM2 slot map matches h's C/D register layout identically (identity pack).
__global__ __launch_bounds__(256) void pack_weights_kernel(
    const float* __restrict__ W1, const float* __restrict__ W2,
    const float* __restrict__ b1, const float* __restrict__ av,
    int4* __restrict__ W1p, int4* __restrict__ W2p, float* __restrict__ avp)
{
    const int idx = blockIdx.x * 256 + threadIdx.x;
    unsigned short vals[8];
    if (idx < 1280) {                      // W1 A-frags: 20 regions x 64 lanes
        const int a = idx >> 6, l = idx & 63;
        const int Mt = a / 5, ks = a - Mt * 5;
        const int row = Mt * 32 + (l & 31), hi = l >> 5;
        #pragma unroll
        for (int e = 0; e < 8; ++e) {
            const int slot = ks * 16 + hi * 8 + e;
            float f;
            if      (slot < 64)  f = W1[(slot + 6) * 128 + row];
            else if (slot < 70)  f = W1[(slot - 64) * 128 + row];
            else if (slot == 70) f = b1[row];
            else                 f = 0.0f;
            vals[e] = f2bf(f);
        }
        int4 v;
        v.x = vals[0] | (vals[1] << 16); v.y = vals[2] | (vals[3] << 16);
        v.z = vals[4] | (vals[5] << 16); v.w = vals[6] | (vals[7] << 16);
        W1p[idx] = v;
    } else if (idx < 2304) {               // W2 B-frags: 16 regions x 64 lanes
        const int i2 = idx - 1280;
        const int rgn = i2 >> 6, l = i2 & 63;
        const int Nt = rgn >> 3, ks2 = rgn & 7;
        const int col = Nt * 32 + (l & 31), hi = l >> 5;
        #pragma unroll
        for (int e = 0; e < 8; ++e) {
            const int Mt = ks2 >> 1;
            const int t  = 2 * (ks2 & 1) + (e >> 2);
            const int c  = e & 3;
            const int hid = Mt * 32 + 4 * (2 * t + hi) + c;
            vals[e] = f2bf(W2[hid * 64 + col]);
        }
        int4 v;
        v.x = vals[0] | (vals[1] << 16); v.y = vals[2] | (vals[3] << 16);
        v.z = vals[4] | (vals[5] << 16); v.w = vals[6] | (vals[7] << 16);
        W2p[i2] = v;
    } else if (idx < 2432) {               // av repacked into C/D reg order
        const int r_ = idx - 2304;         // [Mt][hi][r]
        const int Mt = r_ >> 5, hi = (r_ >> 4) & 1, r = r_ & 15;
        avp[r_] = av[Mt * 32 + 8 * (r >> 2) + 4 * hi + (r & 3)];
    }
}

__global__ __launch_bounds__(512, 4) void it_mfma_kernel(
    const float* __restrict__ y,     // [n_in][3]
    const float* __restrict__ xq,    // [n_out][3]
    const float* __restrict__ f_y,   // [n_in][64]
    const float* __restrict__ b2,    // [64]
    const int*   __restrict__ nbr,   // [n_out*32]
    const int4*  __restrict__ Wall,  // W1p(1280) ++ W2p(1024) ++ avp(128 f32)
    float*       __restrict__ out,   // [n_out][64]
    int n_out)
{
    __shared__ int4  sW[2304];             // 36 KB: W1 frags then W2 frags
    __shared__ float sAv[128];             // av in C/D register order

    const int tid = threadIdx.x;
    const int w   = tid >> 6;              // wave 0..7
    const int l   = tid & 63;              // lane
    const int el  = l & 31;                // this lane's edge
    const int hi  = l >> 5;                // lane half

    const int q = blockIdx.x * WAVES + w;
    const bool active = (q < n_out);
    const int qc = active ? q : 0;

    // nbr early (dependent f_y chain starts during staging)
    const int ni = active ? nbr[qc * KNBR + el] : 0;

    // ---- prologue (only barrier): stage fragments + av into LDS ----
    #pragma unroll
    for (int t = 0; t < 5; ++t) {
        const int idx = tid + t * 512;
        if (idx < 2304) sW[idx] = Wall[idx];
    }
    if (tid < 128) sAv[tid] = ((const float*)(Wall + 2304))[tid];
    __syncthreads();
    const int4* sW1 = sW;                  // region (Mt*5+ks)*64 + lane
    const int4* sW2 = sW + 1280;           // region (Nt*8+ks2)*64 + lane

    if (!active) return;

    // ---------- phase 1: gather edge el into B1 fragments ----------
    const float4* fb = (const float4*)(f_y + (long)ni * 64);
    float4 u0 = fb[ 0 + 2 * hi], u1 = fb[ 1 + 2 * hi];
    float4 u2 = fb[ 4 + 2 * hi], u3 = fb[ 5 + 2 * hi];
    float4 u4 = fb[ 8 + 2 * hi], u5 = fb[ 9 + 2 * hi];
    float4 u6 = fb[12 + 2 * hi], u7 = fb[13 + 2 * hi];

    Frag B1[5];
    B1[0].i.x = cvt_pk_bf16(u0.x, u0.y); B1[0].i.y = cvt_pk_bf16(u0.z, u0.w);
    B1[0].i.z = cvt_pk_bf16(u1.x, u1.y); B1[0].i.w = cvt_pk_bf16(u1.z, u1.w);
    B1[1].i.x = cvt_pk_bf16(u2.x, u2.y); B1[1].i.y = cvt_pk_bf16(u2.z, u2.w);
    B1[1].i.z = cvt_pk_bf16(u3.x, u3.y); B1[1].i.w = cvt_pk_bf16(u3.z, u3.w);
    B1[2].i.x = cvt_pk_bf16(u4.x, u4.y); B1[2].i.y = cvt_pk_bf16(u4.z, u4.w);
    B1[2].i.z = cvt_pk_bf16(u5.x, u5.y); B1[2].i.w = cvt_pk_bf16(u5.z, u5.w);
    B1[3].i.x = cvt_pk_bf16(u6.x, u6.y); B1[3].i.y = cvt_pk_bf16(u6.z, u6.w);
    B1[3].i.z = cvt_pk_bf16(u7.x, u7.y); B1[3].i.w = cvt_pk_bf16(u7.z, u7.w);
    B1[4].i = make_int4(0, 0, 0, 0);
    if (hi == 0) {                         // slots 64..71: coords + bias-1.0
        float2 y01 = *(const float2*)(y + ni * 3);
        float  yz  = y[ni * 3 + 2];
        float2 x01 = *(const float2*)(xq + qc * 3);
        float  xz  = xq[qc * 3 + 2];
        B1[4].i.x = cvt_pk_bf16(y01.x, y01.y);
        B1[4].i.y = cvt_pk_bf16(yz,    x01.x);
        B1[4].i.z = cvt_pk_bf16(x01.y, xz);
        B1[4].i.w = cvt_pk_bf16(1.0f,  0.0f);   // slot 70 = bias edge value
    }

    const f32x16 z16 = {0.f,0.f,0.f,0.f,0.f,0.f,0.f,0.f,
                        0.f,0.f,0.f,0.f,0.f,0.f,0.f,0.f};

    // ---------- phase 2+3: GEMM1 (Mtile pairs) + packed gelu + score + A2 ---
    Frag A2[8];
    f32x2 scv = {0.f, 0.f};
    #pragma unroll
    for (int p = 0; p < 2; ++p) {
        f32x16 aA = z16, aB = z16;
        #pragma unroll
        for (int ks = 0; ks < 5; ++ks) {
            Frag wa0, wa1;
            wa0.i = sW1[((2 * p + 0) * 5 + ks) * 64 + l];
            wa1.i = sW1[((2 * p + 1) * 5 + ks) * 64 + l];
            aA = __builtin_amdgcn_mfma_f32_32x32x16_bf16(wa0.b, B1[ks].b, aA, 0, 0, 0);
            aB = __builtin_amdgcn_mfma_f32_32x32x16_bf16(wa1.b, B1[ks].b, aB, 0, 0, 0);
        }
        #pragma unroll
        for (int m = 0; m < 2; ++m) {
            const f32x16 ac = m ? aB : aA;
            const int Mt = 2 * p + m;
            const float* avb = sAv + Mt * 32 + hi * 16;
            float4 av0 = *(const float4*)(avb + 0);
            float4 av1 = *(const float4*)(avb + 4);
            float4 av2 = *(const float4*)(avb + 8);
            float4 av3 = *(const float4*)(avb + 12);
            f32x2 avv[8] = {{av0.x, av0.y}, {av0.z, av0.w},
                            {av1.x, av1.y}, {av1.z, av1.w},
                            {av2.x, av2.y}, {av2.z, av2.w},
                            {av3.x, av3.y}, {av3.z, av3.w}};
            unsigned hw[8];
            #pragma unroll
            for (int i = 0; i < 8; ++i) {
                f32x2 vin = {ac[2 * i], ac[2 * i + 1]};
                f32x2 hv = fast_gelu2(vin);
                scv = __builtin_elementwise_fma(hv, avv[i], scv);
                hw[i] = cvt_pk_bf16(hv.x, hv.y);
            }
            A2[2 * Mt + 0].i.x = hw[0];
            A2[2 * Mt + 0].i.y = hw[1];
            A2[2 * Mt + 0].i.z = hw[2];
            A2[2 * Mt + 0].i.w = hw[3];
            A2[2 * Mt + 1].i.x = hw[4];
            A2[2 * Mt + 1].i.y = hw[5];
            A2[2 * Mt + 1].i.z = hw[6];
            A2[2 * Mt + 1].i.w = hw[7];
        }
    }

    // ---------- phase 4: softmax (edge el per lane) ----------
    float sc = scv.x + scv.y;
    sc += __shfl_xor(sc, 32, 64);          // sum over lane halves (hidden split)
    float mx = sc;
    mx = fmaxf(mx, __shfl_xor(mx, 1, 64));
    mx = fmaxf(mx, __shfl_xor(mx, 2, 64));
    mx = fmaxf(mx, __shfl_xor(mx, 4, 64));
    mx = fmaxf(mx, __shfl_xor(mx, 8, 64));
    mx = fmaxf(mx, __shfl_xor(mx, 16, 64));
    float ex = __expf(sc - mx);
    float sm = ex;
    sm += __shfl_xor(sm, 1, 64);
    sm += __shfl_xor(sm, 2, 64);
    sm += __shfl_xor(sm, 4, 64);
    sm += __shfl_xor(sm, 8, 64);
    sm += __shfl_xor(sm, 16, 64);
    const float alpha = __fdividef(ex, sm);    // alpha[edge el]

    // ---------- phase 5: GEMM2 (D[edge][out], K=128 over 8 steps) ----------
    f32x16 o0 = z16, o1 = z16;
    #pragma unroll
    for (int ks2 = 0; ks2 < 8; ++ks2) {
        Frag w0, w1;
        w0.i = sW2[(0 * 8 + ks2) * 64 + l];
        w1.i = sW2[(1 * 8 + ks2) * 64 + l];
        o0 = __builtin_amdgcn_mfma_f32_32x32x16_bf16(A2[ks2].b, w0.b, o0, 0, 0, 0);
        o1 = __builtin_amdgcn_mfma_f32_32x32x16_bf16(A2[ks2].b, w1.b, o1, 0, 0, 0);
    }

    // ---------- phase 6: alpha-weighted edge reduce + store ----------
    float ar[16];
    #pragma unroll
    for (int r = 0; r < 16; ++r)
        ar[r] = __shfl(alpha, 8 * (r >> 2) + 4 * hi + (r & 3), 64);

    #pragma unroll
    for (int nt = 0; nt < 2; ++nt) {
        const f32x16 oo = nt ? o1 : o0;
        f32x2 acc = {0.f, 0.f};
        #pragma unroll
        for (int i = 0; i < 8; ++i) {
            f32x2 ov = {oo[2 * i], oo[2 * i + 1]};
            f32x2 av2 = {ar[2 * i], ar[2 * i + 1]};
            acc = __builtin_elementwise_fma(ov, av2, acc);
        }
        float o = acc.x + acc.y;
        o += __shfl_xor(o, 32, 64);        // sum the two lane halves' edges
        if (l < 32)
            out[qc * 64 + nt * 32 + l] = o + b2[nt * 32 + l];
    }
}

extern "C" void kernel_launch(void* const* d_in, const int* in_sizes, int n_in,
                              void* d_out, int out_size, void* d_ws, size_t ws_size,
                              hipStream_t stream) {
    const float* y   = (const float*)d_in[0];
    const float* xq  = (const float*)d_in[1];
    const float* f_y = (const float*)d_in[2];
    const float* W1  = (const float*)d_in[3];
    const float* b1  = (const float*)d_in[4];
    const float* W2  = (const float*)d_in[5];
    const float* b2  = (const float*)d_in[6];
    const float* av  = (const float*)d_in[7];
    const int*   nbr = (const int*)d_in[8];
    float* out = (float*)d_out;

    const int n_out = in_sizes[1] / 3;      // x is [n_out][3]

    int4*  W1p = (int4*)d_ws;               // 1280 frags = 20 KB
    int4*  W2p = W1p + 1280;                // 1024 frags = 16 KB
    float* avp = (float*)(W1p + 2304);      // 128 floats

    pack_weights_kernel<<<10, 256, 0, stream>>>(W1, W2, b1, av, W1p, W2p, avp);
    const int nblk = (n_out + WAVES - 1) / WAVES;
    it_mfma_kernel<<<nblk, 512, 0, stream>>>(y, xq, f_y, b2, nbr,
                                             W1p, out, n_out);
}